// Round 4
// baseline (1847.371 us; speedup 1.0000x reference)
//
#include <hip/hip_runtime.h>
#include <hip/hip_bf16.h>
#include <math.h>

// Problem dims
#define NB 32
#define NS 128
#define NT 64
#define NV 32000
#define NE 256
#define NH 512

typedef short s16x8 __attribute__((ext_vector_type(8)));
typedef float f32x4 __attribute__((ext_vector_type(4)));

__device__ __forceinline__ unsigned short f2bf(float x) {
    union { float f; unsigned u; } v; v.f = x;
    unsigned r = v.u + 0x7FFFu + ((v.u >> 16) & 1u);   // RNE
    return (unsigned short)(r >> 16);
}
__device__ __forceinline__ float bf2f(short h) {
    union { unsigned u; float f; } x;
    x.u = ((unsigned)(unsigned short)h) << 16;
    return x.f;
}

// per-wave wait: lanes 0-31 poll the 32 per-block flags (64B apart) until all
// >= seq. Relaxed atomic loads (LLC-coherent), no RMW, no sleep.
__device__ __forceinline__ void wait_flags(unsigned* flags, unsigned seq) {
    const int lane = threadIdx.x & 63;
    for (;;) {
        unsigned v = 0xFFFFFFFFu;
        if (lane < 32)
            v = __hip_atomic_load(&flags[lane * 16], __ATOMIC_RELAXED, __HIP_MEMORY_SCOPE_AGENT);
        if (__all(v >= seq)) break;
    }
    asm volatile("" ::: "memory");
}

// ---------------------------------------------------------------------------
// K0: pack W_s = [W_prev | Wh_g[:, :512] | Wh]  (512 x 1536) into MFMA
// B-fragment order: tile (ct,kt) holds B[k][c] for c=ct*16+(lane&15),
// k=kt*32+(lane>>4)*8+j.
// ---------------------------------------------------------------------------
__global__ void build_wfrag_k(const float* __restrict__ Wp,
                              const float* __restrict__ Whg,
                              const float* __restrict__ Wh,
                              unsigned short* __restrict__ wfrag) {
    int blk = blockIdx.x;            // = ct*16 + kt ; ct<96, kt<16
    int lane = threadIdx.x;
    int ct = blk >> 4, kt = blk & 15;
    int c = ct * 16 + (lane & 15);
    int kb = kt * 32 + (lane >> 4) * 8;
    s16x8 v;
#pragma unroll
    for (int j = 0; j < 8; ++j) {
        int k = kb + j;
        float x;
        if (c < 512)       x = Wp[k * 512 + c];
        else if (c < 1024) x = Whg[k * 1024 + (c - 512)];
        else               x = Wh[k * 512 + (c - 1024)];
        v[j] = (short)f2bf(x);
    }
    ((s16x8*)wfrag)[blk * 64 + lane] = v;
}

// ---------------------------------------------------------------------------
// Generic MFMA bf16 GEMM, 128x128 tile, BK=32, 4 waves (each 64x64 = 4x4 frags)
// MODE 0 (PRE): A=hiddens f32 [4096][1024]; B packed {W_enc|Wc_g[:, :512]|Wc};
//   epilogue: cols [0,512)->Ta_bf16[s][h]=tanh(v+b_enc); [512,1024)->hWcg_t
//   bf16 TRANSPOSED [b][h][s]; rest->hWc_t (same transposed layout).
// MODE 1 (XP):  A=embed rows gathered by target [2048][256]; B={Wi_g[:, :512]|Wi};
//   epilogue adds summed gate biases; out xgxs f32 [2048][1024]
// MODE 2 (OUT): A=dh bf16 [2048][512]; B=W_out [512][32000]; out = v + 1.5*b_out
// ---------------------------------------------------------------------------
template<int MODE>
__global__ __launch_bounds__(256, 2) void gemm_mfma(
    const float* __restrict__ Af, const unsigned short* __restrict__ Abf,
    const int* __restrict__ gidx,
    const float* __restrict__ B0, const float* __restrict__ B1, const float* __restrict__ B2,
    const float* __restrict__ e0, const float* __restrict__ e1, const float* __restrict__ e2,
    const float* __restrict__ e3, const float* __restrict__ e4, const float* __restrict__ e5,
    void* __restrict__ O0v, void* __restrict__ O1v, void* __restrict__ O2v)
{
    constexpr int M   = (MODE == 0) ? 4096 : 2048;
    constexpr int K   = (MODE == 0) ? 1024 : ((MODE == 1) ? 256 : 512);
    constexpr int LDA = (MODE == 0) ? 1024 : ((MODE == 1) ? 256 : 512);
    constexpr int MB  = M / 128;

    const int bm = blockIdx.x % MB, bn = blockIdx.x / MB;
    const int m0 = bm * 128, n0 = bn * 128;

    const float* Bp; int ldb, coff;
    if constexpr (MODE == 0) {
        int sub = n0 >> 9;
        Bp   = (sub == 0) ? B0 : (sub == 1) ? B1 : B2;
        ldb  = (sub == 1) ? 1024 : 512;
        coff = n0 & 511;
    } else if constexpr (MODE == 1) {
        if (n0 < 512) { Bp = B0; ldb = 1024; coff = n0; }
        else          { Bp = B1; ldb = 512;  coff = n0 - 512; }
    } else {
        Bp = B0; ldb = 32000; coff = n0;
    }

    __shared__ unsigned short As[128 * 40];
    __shared__ unsigned short Bs[128 * 40];

    const int tid = threadIdx.x, lane = tid & 63, w = tid >> 6;
    const int wr = w >> 1, wc = w & 1;
    const int k0f = (lane >> 4) * 8;
    const int rsel = lane & 15;

    f32x4 acc[4][4];
#pragma unroll
    for (int i = 0; i < 4; ++i)
#pragma unroll
        for (int j = 0; j < 4; ++j) { f32x4 z = {0.f, 0.f, 0.f, 0.f}; acc[i][j] = z; }

    for (int kt = 0; kt < K / 32; ++kt) {
        const int k0 = kt * 32;
        __syncthreads();
#pragma unroll
        for (int i = 0; i < 16; ++i) {
            int idx = tid + i * 256;
            int r = idx >> 5, k = idx & 31;
            unsigned short v;
            if constexpr (MODE == 2) {
                v = Abf[(size_t)(m0 + r) * LDA + k0 + k];
            } else if constexpr (MODE == 1) {
                int g = gidx[m0 + r];
                v = f2bf(Af[(size_t)g * 256 + k0 + k]);
            } else {
                v = f2bf(Af[(size_t)(m0 + r) * LDA + k0 + k]);
            }
            As[r * 40 + k] = v;
        }
#pragma unroll
        for (int i = 0; i < 16; ++i) {
            int idx = tid + i * 256;
            int k = idx >> 7, c = idx & 127;
            Bs[c * 40 + k] = f2bf(Bp[(size_t)(k0 + k) * ldb + coff + c]);
        }
        __syncthreads();

        s16x8 af[4], bf[4];
#pragma unroll
        for (int i = 0; i < 4; ++i)
            af[i] = *(const s16x8*)&As[(wr * 64 + i * 16 + rsel) * 40 + k0f];
#pragma unroll
        for (int j = 0; j < 4; ++j)
            bf[j] = *(const s16x8*)&Bs[(wc * 64 + j * 16 + rsel) * 40 + k0f];
#pragma unroll
        for (int i = 0; i < 4; ++i)
#pragma unroll
            for (int j = 0; j < 4; ++j)
                acc[i][j] = __builtin_amdgcn_mfma_f32_16x16x32_bf16(af[i], bf[j], acc[i][j], 0, 0, 0);
    }

    // epilogue: row=(lane>>4)*4+reg, col=lane&15 within each 16x16 frag
    const int rg = (lane >> 4) * 4;
#pragma unroll
    for (int i = 0; i < 4; ++i)
#pragma unroll
        for (int j = 0; j < 4; ++j) {
            int row0 = m0 + wr * 64 + i * 16 + rg;
            int col  = n0 + wc * 64 + j * 16 + rsel;
            if constexpr (MODE == 0) {
                int sub = col >> 9;
                if (sub == 0) {
                    unsigned short* Ta = (unsigned short*)O0v;
#pragma unroll
                    for (int r = 0; r < 4; ++r)
                        Ta[(size_t)(row0 + r) * 512 + col] = f2bf(tanhf(acc[i][j][r] + e0[col]));
                } else {
                    int h = col & 511;
                    int bb = row0 >> 7, s0 = row0 & 127;   // s0 is 4-aligned
                    unsigned long long pk = 0;
#pragma unroll
                    for (int r = 0; r < 4; ++r)
                        pk |= (unsigned long long)f2bf(acc[i][j][r]) << (16 * r);
                    unsigned short* dstp = (sub == 1) ? (unsigned short*)O1v : (unsigned short*)O2v;
                    *(unsigned long long*)&dstp[(size_t)((bb * 512 + h) * 128 + s0)] = pk;
                }
            } else if constexpr (MODE == 1) {
                float* Of = (float*)O0v;
                float bias;
                if (col < 512) bias = e0[col] + e1[col] + e2[col];
                else { int h = col - 512; bias = e3[h] + e4[h] + e5[h]; }
#pragma unroll
                for (int r = 0; r < 4; ++r)
                    Of[(size_t)(row0 + r) * 1024 + col] = acc[i][j][r] + bias;
            } else {
                float* Of = (float*)O0v;
#pragma unroll
                for (int r = 0; r < 4; ++r)
                    Of[(size_t)(row0 + r) * 32000 + col] = acc[i][j][r] + 1.5f * e0[col];
            }
        }
}

// ---------------------------------------------------------------------------
// K3: persistent cooperative scan, flag-synced. 32 blocks x 1024 threads.
// Per-block flags (seq numbers) replace counters: no RMW contention, per-WAVE
// waits, flag posted by an idle wave once an LDS done-counter confirms all
// producer waves drained (vmcnt(0)) their relaxed-atomic publishes.
// MFMA A-operand (state S) loaded straight L3->regs: no LDS staging/conflict.
// ---------------------------------------------------------------------------
__global__ __launch_bounds__(1024) void scan_coop(
    const float* __restrict__ content, const float* __restrict__ sentiment,
    const float* __restrict__ b_prev,  const float* __restrict__ W_att,
    const unsigned short* __restrict__ Ta_bf,
    const unsigned short* __restrict__ hWcg_t,
    const unsigned short* __restrict__ hWc_t,
    const float* __restrict__ xgxs, const unsigned short* __restrict__ wfrag,
    unsigned* __restrict__ S32, float* __restrict__ Ug,
    unsigned* __restrict__ flagS, unsigned* __restrict__ flagU,
    unsigned short* __restrict__ dh)
{
    const int b = blockIdx.x;
    const int tid = threadIdx.x, lane = tid & 63, w = tid >> 6;
    const unsigned long long* S64 = (const unsigned long long*)S32;

    __shared__ unsigned short W_lds[3 * 16 * 64 * 8];   // 48 KB, col-slice frags
    __shared__ float tq[512];
    __shared__ float sc[128], al[128];
    __shared__ float s_f[512];
    __shared__ float cg[512], cs[512];
    __shared__ unsigned ctrA[64], ctrS[64];

    if (tid < 64) ctrA[tid] = 0;
    else if (tid < 128) ctrS[tid - 64] = 0;

    // load weight slice once (ctiles [3b, 3b+3))
    {
        const s16x8* src = (const s16x8*)wfrag + (size_t)b * (3 * 16 * 64);
        s16x8* dst = (s16x8*)W_lds;
        for (int i = tid; i < 3 * 16 * 64; i += 1024) dst[i] = src[i];
    }
    float senth = 0.f, bprev_h = 0.f;
    if (tid < 512) {
        float v = content[b * 512 + tid];
        s_f[tid] = v;
        senth = 0.5f * sentiment[b * 512 + tid];
        bprev_h = b_prev[tid];
    }
    float wv[8];
    {
        const f32x4* wa = (const f32x4*)&W_att[lane * 8];
        f32x4 a0 = wa[0], a1 = wa[1];
#pragma unroll
        for (int j = 0; j < 4; ++j) { wv[j] = a0[j]; wv[4 + j] = a1[j]; }
    }
    __syncthreads();

    // initial publish of S(0) (pair-packed u32, even lanes), seq 1
    if (tid < 512) {
        float ns = s_f[tid];
        float nsn = __shfl_down(ns, 1, 64);
        if (!(lane & 1)) {
            unsigned p = (unsigned)f2bf(ns) | ((unsigned)f2bf(nsn) << 16);
            __hip_atomic_store(&S32[b * 256 + (tid >> 1)], p, __ATOMIC_RELAXED, __HIP_MEMORY_SCOPE_AGENT);
        }
        asm volatile("s_waitcnt vmcnt(0)" ::: "memory");
        if (lane == 0) atomicAdd(&ctrS[0], 1u);
    }
    if (w == 8 && lane == 0) {
        while (__hip_atomic_load(&ctrS[0], __ATOMIC_RELAXED, __HIP_MEMORY_SCOPE_WORKGROUP) < 8) {}
        __hip_atomic_store(&flagS[b * 16], 1u, __ATOMIC_RELAXED, __HIP_MEMORY_SCOPE_AGENT);
    }

    for (int t = 0; t < 64; ++t) {
        // ---- Phase A: U[:, my 48 cols] = S @ Wslice (waves 0..5) ----
        if (w < 6) {
            wait_flags(flagS, (unsigned)(t + 1));
            const int mt = w & 1, ct = w >> 1;
            const int arow = mt * 16 + (lane & 15);
            const int koff = (lane >> 4) * 2;
            unsigned long long sa0[16], sa1[16];
#pragma unroll
            for (int kt = 0; kt < 8; ++kt) {
                sa0[2 * kt]     = __hip_atomic_load(&S64[arow * 128 + kt * 8 + koff],     __ATOMIC_RELAXED, __HIP_MEMORY_SCOPE_AGENT);
                sa0[2 * kt + 1] = __hip_atomic_load(&S64[arow * 128 + kt * 8 + koff + 1], __ATOMIC_RELAXED, __HIP_MEMORY_SCOPE_AGENT);
            }
#pragma unroll
            for (int kt = 0; kt < 8; ++kt) {
                sa1[2 * kt]     = __hip_atomic_load(&S64[arow * 128 + (kt + 8) * 8 + koff],     __ATOMIC_RELAXED, __HIP_MEMORY_SCOPE_AGENT);
                sa1[2 * kt + 1] = __hip_atomic_load(&S64[arow * 128 + (kt + 8) * 8 + koff + 1], __ATOMIC_RELAXED, __HIP_MEMORY_SCOPE_AGENT);
            }
            f32x4 a4 = {0.f, 0.f, 0.f, 0.f};
            const s16x8* wl = (const s16x8*)W_lds;
#pragma unroll
            for (int kt = 0; kt < 8; ++kt) {
                union { unsigned long long q[2]; s16x8 v; } u;
                u.q[0] = sa0[2 * kt]; u.q[1] = sa0[2 * kt + 1];
                s16x8 bfr = wl[(ct * 16 + kt) * 64 + lane];
                a4 = __builtin_amdgcn_mfma_f32_16x16x32_bf16(u.v, bfr, a4, 0, 0, 0);
            }
#pragma unroll
            for (int kt = 0; kt < 8; ++kt) {
                union { unsigned long long q[2]; s16x8 v; } u;
                u.q[0] = sa1[2 * kt]; u.q[1] = sa1[2 * kt + 1];
                s16x8 bfr = wl[(ct * 16 + kt + 8) * 64 + lane];
                a4 = __builtin_amdgcn_mfma_f32_16x16x32_bf16(u.v, bfr, a4, 0, 0, 0);
            }
            const int cout = b * 48 + ct * 16 + (lane & 15);
            const int rbase = mt * 16 + (lane >> 4) * 4;
#pragma unroll
            for (int r = 0; r < 4; ++r)
                __hip_atomic_store(&Ug[(rbase + r) * 1536 + cout], a4[r],
                                   __ATOMIC_RELAXED, __HIP_MEMORY_SCOPE_AGENT);
            asm volatile("s_waitcnt vmcnt(0)" ::: "memory");
            if (lane == 0) atomicAdd(&ctrA[t], 1u);
        }
        if (w == 6 && lane == 0) {
            while (__hip_atomic_load(&ctrA[t], __ATOMIC_RELAXED, __HIP_MEMORY_SCOPE_WORKGROUP) < 6) {}
            __hip_atomic_store(&flagU[b * 16], (unsigned)(t + 1), __ATOMIC_RELAXED, __HIP_MEMORY_SCOPE_AGENT);
        }

        // ---- Phase B: fetch my row of U; tq = tanh(q + b_prev) ----
        float guv = 0.f, suv = 0.f;
        if (tid < 512) {
            wait_flags(flagU, (unsigned)(t + 1));
            float qv = __hip_atomic_load(&Ug[b * 1536 + tid],        __ATOMIC_RELAXED, __HIP_MEMORY_SCOPE_AGENT);
            guv      = __hip_atomic_load(&Ug[b * 1536 + 512 + tid],  __ATOMIC_RELAXED, __HIP_MEMORY_SCOPE_AGENT);
            suv      = __hip_atomic_load(&Ug[b * 1536 + 1024 + tid], __ATOMIC_RELAXED, __HIP_MEMORY_SCOPE_AGENT);
            tq[tid] = tanhf(qv + bprev_h);
        }
        __syncthreads();
        // scores via tanh(a+q) = (Ta+tq)/(1+Ta*tq); wave w -> positions w*8..+8
        {
            float tqv[8];
            {
                const f32x4* tp = (const f32x4*)&tq[lane * 8];
                f32x4 t0 = tp[0], t1 = tp[1];
#pragma unroll
                for (int j = 0; j < 4; ++j) { tqv[j] = t0[j]; tqv[4 + j] = t1[j]; }
            }
#pragma unroll
            for (int s8 = 0; s8 < 8; ++s8) {
                int s = w * 8 + s8;
                s16x8 tv = *(const s16x8*)&Ta_bf[((size_t)(b * 128 + s)) * 512 + lane * 8];
                float a = 0.f;
#pragma unroll
                for (int j = 0; j < 8; ++j) {
                    float ta = bf2f(tv[j]);
                    float num = ta + tqv[j];
                    float den = fmaf(ta, tqv[j], 1.0f);
                    a = fmaf(wv[j], num * __builtin_amdgcn_rcpf(den), a);
                }
#pragma unroll
                for (int off = 32; off; off >>= 1) a += __shfl_xor(a, off, 64);
                if (lane == 0) sc[s] = a;
            }
        }
        __syncthreads();
        // softmax over 128 (wave 0)
        if (w == 0) {
            float v0 = sc[lane], v1 = sc[lane + 64];
            float m = fmaxf(v0, v1);
#pragma unroll
            for (int off = 32; off; off >>= 1) m = fmaxf(m, __shfl_xor(m, off, 64));
            float p0 = __expf(v0 - m), p1 = __expf(v1 - m);
            float sm = p0 + p1;
#pragma unroll
            for (int off = 32; off; off >>= 1) sm += __shfl_xor(sm, off, 64);
            float inv = __builtin_amdgcn_rcpf(sm);
            al[lane] = p0 * inv; al[lane + 64] = p1 * inv;
        }
        __syncthreads();
        // ---- Phase C: ctx: thread = one h of one matrix; 16x contiguous b128
        {
            int mat = tid >> 9, h = tid & 511;
            const s16x8* Mp = (const s16x8*)((mat ? hWc_t : hWcg_t) + ((size_t)(b * 512 + h)) * 128);
            float a0 = 0.f, a1 = 0.f;
#pragma unroll
            for (int q = 0; q < 16; ++q) {
                s16x8 v = Mp[q];
#pragma unroll
                for (int j = 0; j < 8; j += 2) {
                    a0 = fmaf(al[q * 8 + j],     bf2f(v[j]),     a0);
                    a1 = fmaf(al[q * 8 + j + 1], bf2f(v[j + 1]), a1);
                }
            }
            if (mat) cs[h] = a0 + a1; else cg[h] = a0 + a1;
        }
        __syncthreads();
        // ---- Phase D: gate + state update + publish ----
        if (tid < 512) {
            int h = tid;
            size_t row = (size_t)b * 64 + t;
            float g  = guv + xgxs[row * 1024 + h]       + cg[h];
            float r  = __builtin_amdgcn_rcpf(1.0f + __expf(-g));
            float sp = suv + xgxs[row * 1024 + 512 + h] + cs[h];
            float e  = __expf(2.0f * sp);
            float st = 1.0f - 2.0f * __builtin_amdgcn_rcpf(e + 1.0f);
            float sold = s_f[h];
            float ns = sold + r * (st - sold);
            s_f[h] = ns;
            dh[row * 512 + h] = f2bf(ns + senth);
            float nsn = __shfl_down(ns, 1, 64);
            if (t < 63) {
                if (!(lane & 1)) {
                    unsigned p = (unsigned)f2bf(ns) | ((unsigned)f2bf(nsn) << 16);
                    __hip_atomic_store(&S32[b * 256 + (tid >> 1)], p, __ATOMIC_RELAXED, __HIP_MEMORY_SCOPE_AGENT);
                }
                asm volatile("s_waitcnt vmcnt(0)" ::: "memory");
                if (lane == 0) atomicAdd(&ctrS[t + 1], 1u);
            }
        }
        if (t < 63 && w == 8 && lane == 0) {
            while (__hip_atomic_load(&ctrS[t + 1], __ATOMIC_RELAXED, __HIP_MEMORY_SCOPE_WORKGROUP) < 8) {}
            __hip_atomic_store(&flagS[b * 16], (unsigned)(t + 2), __ATOMIC_RELAXED, __HIP_MEMORY_SCOPE_AGENT);
        }
    }
}

// ---------------------------------------------------------------------------
extern "C" void kernel_launch(void* const* d_in, const int* in_sizes, int n_in,
                              void* d_out, int out_size, void* d_ws, size_t ws_size,
                              hipStream_t stream) {
    const float* content  = (const float*)d_in[0];
    const float* sentiment= (const float*)d_in[1];
    const float* hiddens  = (const float*)d_in[2];
    const int*   target   = (const int*)  d_in[3];
    const float* embed    = (const float*)d_in[4];
    const float* W_enc = (const float*)d_in[5];  const float* b_enc = (const float*)d_in[6];
    const float* W_prev= (const float*)d_in[7];  const float* b_prev= (const float*)d_in[8];
    const float* W_att = (const float*)d_in[9];  /* b_att (d_in[10]) cancels in softmax */
    const float* Wi_g  = (const float*)d_in[11]; const float* bi_g  = (const float*)d_in[12];
    const float* Wh_g  = (const float*)d_in[13]; const float* bh_g  = (const float*)d_in[14];
    const float* Wc_g  = (const float*)d_in[15]; const float* bc_g  = (const float*)d_in[16];
    const float* Wi    = (const float*)d_in[17]; const float* bi    = (const float*)d_in[18];
    const float* Wh    = (const float*)d_in[19]; const float* bh    = (const float*)d_in[20];
    const float* Wc    = (const float*)d_in[21]; const float* bc    = (const float*)d_in[22];
    const float* W_out = (const float*)d_in[23]; const float* b_out = (const float*)d_in[24];
    float* out = (float*)d_out;

    // workspace layout (bytes)
    char* ws = (char*)d_ws;
    unsigned short* wfrag = (unsigned short*)ws;                       // 1.5 MB @0
    unsigned* flagS = (unsigned*)(ws + 0x180000);                      // 2 KB (32 x 64B)
    unsigned* flagU = (unsigned*)(ws + 0x180800);                      // 2 KB
    float* Ug       = (float*)(ws + 0x181000);                         // 192 KB [32][1536]
    unsigned short* Ta_bf   = (unsigned short*)(ws + 0x1B1000);        // 4 MB [4096][512]
    unsigned short* hWcg_t  = (unsigned short*)(ws + 0x5B1000);        // 4 MB [32][512][128]
    unsigned short* hWc_t   = (unsigned short*)(ws + 0x9B1000);        // 4 MB
    float* xgxs     = (float*)(ws + 0xDB1000);                         // 8 MB [2048][1024]
    unsigned short* dh      = (unsigned short*)(ws + 0x15B1000);       // 2 MB [2048][512]
    unsigned* S32   = (unsigned*)(ws + 0x17B1000);                     // 32 KB [32][256] u32

    // zero flags every launch (graph-capturable)
    hipMemsetAsync(ws + 0x180000, 0, 4096, stream);

    // K0: pack recurrent weight fragments
    build_wfrag_k<<<96 * 16, 64, 0, stream>>>(W_prev, Wh_g, Wh, wfrag);

    // K1: PRE gemm -> Ta_bf (tanh, bf16), hWcg_t/hWc_t (bf16 transposed)
    gemm_mfma<0><<<32 * 12, 256, 0, stream>>>(
        hiddens, nullptr, nullptr, W_enc, Wc_g, Wc,
        b_enc, nullptr, nullptr, nullptr, nullptr, nullptr,
        (void*)Ta_bf, (void*)hWcg_t, (void*)hWc_t);

    // K2: XP gemm -> xgxs = [emb@Wi_g' + (bi_g+bh_g+bc_g)' | emb@Wi + (bi+bh+bc)]
    gemm_mfma<1><<<16 * 8, 256, 0, stream>>>(
        embed, nullptr, target, Wi_g, Wi, nullptr,
        bi_g, bh_g, bc_g, bi, bh, bc,
        (void*)xgxs, nullptr, nullptr);

    // K3: persistent scan -> dh
    scan_coop<<<NB, 1024, 0, stream>>>(
        content, sentiment, b_prev, W_att, Ta_bf, hWcg_t, hWc_t,
        xgxs, wfrag, S32, Ug, flagS, flagU, dh);

    // K4: OUT gemm -> d_out = dh@W_out + 1.5*b_out
    gemm_mfma<2><<<16 * 250, 256, 0, stream>>>(
        nullptr, dh, nullptr, W_out, nullptr, nullptr,
        b_out, nullptr, nullptr, nullptr, nullptr, nullptr,
        (void*)out, nullptr, nullptr);

    (void)in_sizes; (void)n_in; (void)out_size; (void)ws_size;
}